// Round 9
// baseline (1556.240 us; speedup 1.0000x reference)
//
#include <hip/hip_runtime.h>
#include <hip/hip_bf16.h>
#include <hip/hip_fp16.h>

#define N_NODES 100000
#define N_EDGES 1600000
#define D 128
#define NBUK 391                 // ceil(N_NODES / 256); bucket = 256 nodes
#define CAP 5120                 // bin capacity per bucket (mean 4096, sigma 64)
#define EPB 8192                 // edges per block in binning pass
#define NB_E ((N_EDGES + EPB - 1) / EPB)   // 196

// ---------------------------------------------------------------------------
// bin_scatter_direct (single pass): LDS-count this block's edges per bucket,
// reserve [b*CAP + cnt[b], ...) with one global atomic per (block,bucket),
// then write bin entries. dstbin packs (src<<8)|dst_local; srcbin = src&255.
// cnt_d / cnt_s end up holding the final per-bucket counts.
// ---------------------------------------------------------------------------
__global__ __launch_bounds__(256) void bin_scatter_kernel(const int* __restrict__ ei,
                                                          int* __restrict__ cnt_d,
                                                          int* __restrict__ cnt_s,
                                                          unsigned int* __restrict__ dstbin,
                                                          unsigned char* __restrict__ srcbin) {
    __shared__ int cd[NBUK], cs[NBUK];
    __shared__ int bd[NBUK], bs[NBUK];
    const int t = threadIdx.x;
    for (int b = t; b < NBUK; b += 256) { cd[b] = 0; cs[b] = 0; }
    __syncthreads();
    const int e0 = blockIdx.x * EPB;
#pragma unroll
    for (int i = 0; i < EPB / 256; ++i) {
        int e = e0 + i * 256 + t;
        if (e < N_EDGES) {
            atomicAdd(&cs[ei[e] >> 8], 1);
            atomicAdd(&cd[ei[N_EDGES + e] >> 8], 1);
        }
    }
    __syncthreads();
    for (int b = t; b < NBUK; b += 256) {
        bd[b] = cd[b] ? b * CAP + atomicAdd(&cnt_d[b], cd[b]) : 0;
        bs[b] = cs[b] ? b * CAP + atomicAdd(&cnt_s[b], cs[b]) : 0;
        cd[b] = 0; cs[b] = 0;
    }
    __syncthreads();
#pragma unroll
    for (int i = 0; i < EPB / 256; ++i) {
        int e = e0 + i * 256 + t;
        if (e < N_EDGES) {
            int s = ei[e];
            int d = ei[N_EDGES + e];
            int p1 = bd[d >> 8] + atomicAdd(&cd[d >> 8], 1);
            dstbin[p1] = ((unsigned)s << 8) | (unsigned)(d & 255);
            int p2 = bs[s >> 8] + atomicAdd(&cs[s >> 8], 1);
            srcbin[p2] = (unsigned char)(s & 255);
        }
    }
}

// ---------------------------------------------------------------------------
// dis_kernel: one block per bucket; LDS histogram of src_local bytes ->
// dis[node] = rsqrt(deg + 1)  (self loop adds 1).
// ---------------------------------------------------------------------------
__global__ __launch_bounds__(256) void dis_kernel(const unsigned char* __restrict__ srcbin,
                                                  const int* __restrict__ cnt_s,
                                                  float* __restrict__ dis) {
    __shared__ int hist[256];
    const int t = threadIdx.x, b = blockIdx.x;
    hist[t] = 0;
    __syncthreads();
    const unsigned char* sb = srcbin + (size_t)b * CAP;
    const int ns = cnt_s[b];
    for (int i = t * 4; i < ns; i += 1024) {
        uchar4 v = *(const uchar4*)(sb + i);
        if (i + 0 < ns) atomicAdd(&hist[v.x], 1);
        if (i + 1 < ns) atomicAdd(&hist[v.y], 1);
        if (i + 2 < ns) atomicAdd(&hist[v.z], 1);
        if (i + 3 < ns) atomicAdd(&hist[v.w], 1);
    }
    __syncthreads();
    const int node = b * 256 + t;
    if (node < N_NODES) dis[node] = rsqrtf((float)hist[t] + 1.0f);
}

// ---------------------------------------------------------------------------
// GEMM v3 + fp16 epilogue (unchanged, r8-verified):
// hh[r][c] = (half) dis[r]*(b[c] + x[r]·W[c])
// ---------------------------------------------------------------------------
#define BM 32
__global__ __launch_bounds__(256) void gemm_kernel(const float* __restrict__ x,
                                                   const float* __restrict__ W,
                                                   const float* __restrict__ bias,
                                                   const float* __restrict__ dis,
                                                   __half* __restrict__ hh) {
    __shared__ float4 Ws[128 * 32];  // 64 KiB
    __shared__ float4 Xs[32 * 32];   // 16 KiB

    const int t = threadIdx.x;
    const float4* W4 = (const float4*)W;
#pragma unroll
    for (int i = 0; i < 16; ++i) {
        int j = i * 256 + t;
        int c = j >> 5, kg = j & 31;
        Ws[c * 32 + (kg ^ ((c >> 2) & 7))] = W4[j];
    }
    const int row0 = blockIdx.x * BM;
    const float4* X4 = (const float4*)(x + (size_t)row0 * D);
#pragma unroll
    for (int i = 0; i < 4; ++i) {
        int j = i * 256 + t;
        int r = j >> 5, kg = j & 31;
        Xs[r * 32 + (kg ^ ((r >> 2) & 7))] = X4[j];
    }
    __syncthreads();

    const int rg = t & 7;
    const int cg = t >> 3;
    const int xswz = rg;
    const int wswz = cg & 7;

    float acc[4][4];
#pragma unroll
    for (int a = 0; a < 4; ++a)
#pragma unroll
        for (int c2 = 0; c2 < 4; ++c2) acc[a][c2] = 0.f;

#pragma unroll 2
    for (int kg = 0; kg < 32; ++kg) {
        float4 xv[4], wv[4];
#pragma unroll
        for (int ri = 0; ri < 4; ++ri)
            xv[ri] = Xs[(rg * 4 + ri) * 32 + (kg ^ xswz)];
#pragma unroll
        for (int ci = 0; ci < 4; ++ci)
            wv[ci] = Ws[(cg * 4 + ci) * 32 + (kg ^ wswz)];
#pragma unroll
        for (int ri = 0; ri < 4; ++ri)
#pragma unroll
            for (int ci = 0; ci < 4; ++ci) {
                acc[ri][ci] = fmaf(xv[ri].x, wv[ci].x, acc[ri][ci]);
                acc[ri][ci] = fmaf(xv[ri].y, wv[ci].y, acc[ri][ci]);
                acc[ri][ci] = fmaf(xv[ri].z, wv[ci].z, acc[ri][ci]);
                acc[ri][ci] = fmaf(xv[ri].w, wv[ci].w, acc[ri][ci]);
            }
    }

    const float4 bv = ((const float4*)bias)[cg];
#pragma unroll
    for (int ri = 0; ri < 4; ++ri) {
        int row = row0 + rg * 4 + ri;
        float dv = dis[row];
        __half2 p0 = __floats2half2_rn(dv * (acc[ri][0] + bv.x), dv * (acc[ri][1] + bv.y));
        __half2 p1 = __floats2half2_rn(dv * (acc[ri][2] + bv.z), dv * (acc[ri][3] + bv.w));
        uint2 u;
        u.x = *(unsigned int*)&p0;
        u.y = *(unsigned int*)&p1;
        ((uint2*)(hh + (size_t)row * D))[cg] = u;
    }
}

// ---------------------------------------------------------------------------
// gather_acc: one 1024-thread block per bucket; full 256x128 fp32 accumulator
// in LDS (128 KB). Lane l owns cols (2l, 2l+1) stored at LDS positions l and
// 64+l (bank = l%32, 2-way aliasing = free). Each wave streams its slice of
// the bucket's dstbin: uint4 broadcast of 4 edge descriptors, 4 independent
// hh-row uint loads in flight, 2 ds_add_f32 per edge. Epilogue fuses
// self-loop + ReLU + 0.125 scale; coalesced float2 writes.
// ---------------------------------------------------------------------------
__global__ __launch_bounds__(1024) void gather_acc_kernel(const unsigned int* __restrict__ dstbin,
                                                          const int* __restrict__ cnt_d,
                                                          const float* __restrict__ dis,
                                                          const __half* __restrict__ hh,
                                                          float* __restrict__ out) {
    __shared__ float acc[256 * 128];   // 128 KiB
    const int t = threadIdx.x, b = blockIdx.x;
    const int w = t >> 6, l = t & 63;

    float4* a4 = (float4*)acc;
#pragma unroll
    for (int i = 0; i < 8; ++i) a4[t + i * 1024] = make_float4(0.f, 0.f, 0.f, 0.f);
    __syncthreads();

    const unsigned int* bin = dstbin + (size_t)b * CAP;
    const unsigned int* hh32 = (const unsigned int*)hh;
    const int nb = cnt_d[b];

    for (int base = w * 4; base < nb; base += 64) {
        uint4 ed = *(const uint4*)(bin + base);   // 16B-aligned broadcast
#pragma unroll
        for (int k = 0; k < 4; ++k) {
            int e = base + k;
            if (e < nb) {
                unsigned p = (k == 0) ? ed.x : (k == 1) ? ed.y : (k == 2) ? ed.z : ed.w;
                int src  = (int)(p >> 8);
                int dstl = (int)(p & 255u);
                unsigned u = hh32[(size_t)src * 64 + l];
                __half2 q = *(__half2*)&u;
                float2 f = __half22float2(q);
                atomicAdd(&acc[dstl * 128 + l], f.x);
                atomicAdd(&acc[dstl * 128 + 64 + l], f.y);
            }
        }
    }
    __syncthreads();

    // epilogue: wave w handles nodes w*16 .. w*16+15
#pragma unroll
    for (int i = 0; i < 16; ++i) {
        int n = w * 16 + i;
        int node = b * 256 + n;
        if (node >= N_NODES) break;
        float dd = dis[node];
        float sx = acc[n * 128 + l];
        float sy = acc[n * 128 + 64 + l];
        unsigned u = ((const unsigned int*)hh)[(size_t)node * 64 + l];
        __half2 q = *(__half2*)&u;
        float2 f = __half22float2(q);
        float2 o;
        o.x = fmaxf(dd * (sx + f.x), 0.f) * 0.125f;
        o.y = fmaxf(dd * (sy + f.y), 0.f) * 0.125f;
        ((float2*)(out + (size_t)node * D))[l] = o;
    }
}

extern "C" void kernel_launch(void* const* d_in, const int* in_sizes, int n_in,
                              void* d_out, int out_size, void* d_ws, size_t ws_size,
                              hipStream_t stream) {
    const float* x  = (const float*)d_in[0];
    const int*   ei = (const int*)d_in[1];   // [2, E] int32
    const float* W  = (const float*)d_in[2];
    const float* b  = (const float*)d_in[3];
    float* out = (float*)d_out;

    // workspace layout (~36 MB)
    __half*        hh     = (__half*)d_ws;                          // N*D halfs (25.6 MB)
    float*         dis    = (float*)(hh + (size_t)N_NODES * D);     // N floats
    unsigned int*  dstbin = (unsigned int*)(dis + N_NODES);         // NBUK*CAP uints (8 MB)
    unsigned char* srcbin = (unsigned char*)(dstbin + (size_t)NBUK * CAP); // NBUK*CAP bytes (2 MB)
    int*           cnt_d  = (int*)(srcbin + (size_t)NBUK * CAP);    // NBUK ints
    int*           cnt_s  = cnt_d + NBUK;                           // NBUK ints

    hipMemsetAsync(cnt_d, 0, 2 * NBUK * sizeof(int), stream);

    bin_scatter_kernel<<<NB_E, 256, 0, stream>>>(ei, cnt_d, cnt_s, dstbin, srcbin);
    dis_kernel<<<NBUK, 256, 0, stream>>>(srcbin, cnt_s, dis);
    gemm_kernel<<<N_NODES / BM, 256, 0, stream>>>(x, W, b, dis, hh);
    gather_acc_kernel<<<NBUK, 1024, 0, stream>>>(dstbin, cnt_d, dis, hh, out);
}

// Round 12
// 277.524 us; speedup vs baseline: 5.6076x; 5.6076x over previous
//
#include <hip/hip_runtime.h>
#include <hip/hip_bf16.h>
#include <hip/hip_fp16.h>

#define N_NODES 100000
#define N_EDGES 1600000
#define D 128
#define NBUK 391                 // ceil(N_NODES / 256); bucket = 256 nodes
#define CAP 5120                 // padded bin capacity (mean 4096, 16 sigma)
#define EPB 8192                 // edges per block in binning pass
#define NB_E ((N_EDGES + EPB - 1) / EPB)   // 196

// ---------------------------------------------------------------------------
// bin_scatter (r9-verified): single pass. LDS-count this block's edges per
// bucket, reserve [b*CAP + cnt[b] ...) with one global atomic per
// (block,bucket), write bin entries. dstbin packs (src<<8)|dst_local;
// srcbin = src&255. cnt_d/cnt_s end with final per-bucket counts.
// ---------------------------------------------------------------------------
__global__ __launch_bounds__(256) void bin_scatter_kernel(const int* __restrict__ ei,
                                                          int* __restrict__ cnt_d,
                                                          int* __restrict__ cnt_s,
                                                          unsigned int* __restrict__ dstbin,
                                                          unsigned char* __restrict__ srcbin) {
    __shared__ int cd[NBUK], cs[NBUK];
    __shared__ int bd[NBUK], bs[NBUK];
    const int t = threadIdx.x;
    for (int b = t; b < NBUK; b += 256) { cd[b] = 0; cs[b] = 0; }
    __syncthreads();
    const int e0 = blockIdx.x * EPB;
#pragma unroll
    for (int i = 0; i < EPB / 256; ++i) {
        int e = e0 + i * 256 + t;
        if (e < N_EDGES) {
            atomicAdd(&cs[ei[e] >> 8], 1);
            atomicAdd(&cd[ei[N_EDGES + e] >> 8], 1);
        }
    }
    __syncthreads();
    for (int b = t; b < NBUK; b += 256) {
        bd[b] = cd[b] ? b * CAP + atomicAdd(&cnt_d[b], cd[b]) : 0;
        bs[b] = cs[b] ? b * CAP + atomicAdd(&cnt_s[b], cs[b]) : 0;
        cd[b] = 0; cs[b] = 0;
    }
    __syncthreads();
#pragma unroll
    for (int i = 0; i < EPB / 256; ++i) {
        int e = e0 + i * 256 + t;
        if (e < N_EDGES) {
            int s = ei[e];
            int d = ei[N_EDGES + e];
            int p1 = bd[d >> 8] + atomicAdd(&cd[d >> 8], 1);
            dstbin[p1] = ((unsigned)s << 8) | (unsigned)(d & 255);
            int p2 = bs[s >> 8] + atomicAdd(&cs[s >> 8], 1);
            srcbin[p2] = (unsigned char)(s & 255);
        }
    }
}

// ---------------------------------------------------------------------------
// bucket_build (r8-verified logic, padded-bin layout): one block per bucket.
// dst side: LDS hist -> scan -> offs/offe[node] (padded-global), LDS-cursor
// scatter of src into sorted[] (padded region). src side: hist -> dis.
// ---------------------------------------------------------------------------
__global__ __launch_bounds__(256) void bucket_build_kernel(const unsigned int* __restrict__ dstbin,
                                                           const unsigned char* __restrict__ srcbin,
                                                           const int* __restrict__ cnt_d,
                                                           const int* __restrict__ cnt_s,
                                                           int* __restrict__ offs,
                                                           int* __restrict__ offe,
                                                           int* __restrict__ sorted,
                                                           float* __restrict__ dis) {
    __shared__ int hist[256];
    __shared__ int scn[256];
    __shared__ int cur[256];
    const int t = threadIdx.x, b = blockIdx.x;
    const int node = b * 256 + t;
    const int base = b * CAP;

    const int nd = cnt_d[b];
    hist[t] = 0;
    __syncthreads();
    for (int i = t; i < nd; i += 256) atomicAdd(&hist[dstbin[base + i] & 255], 1);
    __syncthreads();
    scn[t] = hist[t];
    __syncthreads();
    for (int o = 1; o < 256; o <<= 1) {
        int v = (t >= o) ? scn[t - o] : 0;
        __syncthreads();
        scn[t] += v;
        __syncthreads();
    }
    const int mys = base + ((t == 0) ? 0 : scn[t - 1]);
    if (node < N_NODES) { offs[node] = mys; offe[node] = base + scn[t]; }
    cur[t] = mys;
    __syncthreads();
    for (int i = t; i < nd; i += 256) {
        unsigned p = dstbin[base + i];
        int pos = atomicAdd(&cur[p & 255], 1);
        sorted[pos] = (int)(p >> 8);
    }

    // src side: degree -> dis
    hist[t] = 0;
    __syncthreads();
    const int ns = cnt_s[b];
    for (int i = t; i < ns; i += 256) atomicAdd(&hist[srcbin[base + i]], 1);
    __syncthreads();
    if (node < N_NODES) dis[node] = rsqrtf((float)hist[t] + 1.0f);
}

// ---------------------------------------------------------------------------
// GEMM v3 + fp16 epilogue (r8-verified, unchanged):
// hh[r][c] = (half) dis[r]*(b[c] + x[r]·W[c])
// ---------------------------------------------------------------------------
#define BM 32
__global__ __launch_bounds__(256) void gemm_kernel(const float* __restrict__ x,
                                                   const float* __restrict__ W,
                                                   const float* __restrict__ bias,
                                                   const float* __restrict__ dis,
                                                   __half* __restrict__ hh) {
    __shared__ float4 Ws[128 * 32];  // 64 KiB
    __shared__ float4 Xs[32 * 32];   // 16 KiB

    const int t = threadIdx.x;
    const float4* W4 = (const float4*)W;
#pragma unroll
    for (int i = 0; i < 16; ++i) {
        int j = i * 256 + t;
        int c = j >> 5, kg = j & 31;
        Ws[c * 32 + (kg ^ ((c >> 2) & 7))] = W4[j];
    }
    const int row0 = blockIdx.x * BM;
    const float4* X4 = (const float4*)(x + (size_t)row0 * D);
#pragma unroll
    for (int i = 0; i < 4; ++i) {
        int j = i * 256 + t;
        int r = j >> 5, kg = j & 31;
        Xs[r * 32 + (kg ^ ((r >> 2) & 7))] = X4[j];
    }
    __syncthreads();

    const int rg = t & 7;
    const int cg = t >> 3;
    const int xswz = rg;
    const int wswz = cg & 7;

    float acc[4][4];
#pragma unroll
    for (int a = 0; a < 4; ++a)
#pragma unroll
        for (int c2 = 0; c2 < 4; ++c2) acc[a][c2] = 0.f;

#pragma unroll 2
    for (int kg = 0; kg < 32; ++kg) {
        float4 xv[4], wv[4];
#pragma unroll
        for (int ri = 0; ri < 4; ++ri)
            xv[ri] = Xs[(rg * 4 + ri) * 32 + (kg ^ xswz)];
#pragma unroll
        for (int ci = 0; ci < 4; ++ci)
            wv[ci] = Ws[(cg * 4 + ci) * 32 + (kg ^ wswz)];
#pragma unroll
        for (int ri = 0; ri < 4; ++ri)
#pragma unroll
            for (int ci = 0; ci < 4; ++ci) {
                acc[ri][ci] = fmaf(xv[ri].x, wv[ci].x, acc[ri][ci]);
                acc[ri][ci] = fmaf(xv[ri].y, wv[ci].y, acc[ri][ci]);
                acc[ri][ci] = fmaf(xv[ri].z, wv[ci].z, acc[ri][ci]);
                acc[ri][ci] = fmaf(xv[ri].w, wv[ci].w, acc[ri][ci]);
            }
    }

    const float4 bv = ((const float4*)bias)[cg];
#pragma unroll
    for (int ri = 0; ri < 4; ++ri) {
        int row = row0 + rg * 4 + ri;
        float dv = dis[row];
        __half2 p0 = __floats2half2_rn(dv * (acc[ri][0] + bv.x), dv * (acc[ri][1] + bv.y));
        __half2 p1 = __floats2half2_rn(dv * (acc[ri][2] + bv.z), dv * (acc[ri][3] + bv.w));
        uint2 u;
        u.x = *(unsigned int*)&p0;
        u.y = *(unsigned int*)&p1;
        ((uint2*)(hh + (size_t)row * D))[cg] = u;
    }
}

// ---------------------------------------------------------------------------
// gather (r8-verified, offs/offe variant): one wave per dst node, half-wave
// row pairing, uint2 (4 halfs) per lane; fp32 accumulate, fused epilogue.
// ---------------------------------------------------------------------------
__global__ __launch_bounds__(256) void gather_kernel(const int* __restrict__ sorted,
                                                     const int* __restrict__ offs,
                                                     const int* __restrict__ offe,
                                                     const float* __restrict__ dis,
                                                     const __half* __restrict__ hh,
                                                     float* __restrict__ out) {
    const int node = blockIdx.x * 4 + (threadIdx.x >> 6);
    const int lane = threadIdx.x & 63;
    if (node >= N_NODES) return;
    const int half = lane >> 5;
    const int l32  = lane & 31;

    const int n0 = offs[node], n1 = offe[node];
    float4 a0 = {0,0,0,0}, a1 = {0,0,0,0}, a2 = {0,0,0,0}, a3 = {0,0,0,0};

#define ACC(A, V) {                                                   \
        __half2 q0 = *(__half2*)&(V).x, q1 = *(__half2*)&(V).y;       \
        float2 f0 = __half22float2(q0), f1 = __half22float2(q1);      \
        (A).x += f0.x; (A).y += f0.y; (A).z += f1.x; (A).w += f1.y; }

    int e = n0;
    for (; e + 8 <= n1; e += 8) {
        int s0 = sorted[e + 0 + half];
        int s1 = sorted[e + 2 + half];
        int s2 = sorted[e + 4 + half];
        int s3 = sorted[e + 6 + half];
        uint2 v0 = ((const uint2*)(hh + (size_t)s0 * D))[l32];
        uint2 v1 = ((const uint2*)(hh + (size_t)s1 * D))[l32];
        uint2 v2 = ((const uint2*)(hh + (size_t)s2 * D))[l32];
        uint2 v3 = ((const uint2*)(hh + (size_t)s3 * D))[l32];
        ACC(a0, v0); ACC(a1, v1); ACC(a2, v2); ACC(a3, v3);
    }
    for (; e + 2 <= n1; e += 2) {
        int s = sorted[e + half];
        uint2 v = ((const uint2*)(hh + (size_t)s * D))[l32];
        ACC(a0, v);
    }
    if (e < n1) {
        int s = sorted[e];
        uint2 v = ((const uint2*)(hh + (size_t)s * D))[l32];
        if (half == 0) ACC(a0, v);
    }
#undef ACC

    float4 tot;
    tot.x = (a0.x + a1.x) + (a2.x + a3.x);
    tot.y = (a0.y + a1.y) + (a2.y + a3.y);
    tot.z = (a0.z + a1.z) + (a2.z + a3.z);
    tot.w = (a0.w + a1.w) + (a2.w + a3.w);
    tot.x += __shfl_xor(tot.x, 32);
    tot.y += __shfl_xor(tot.y, 32);
    tot.z += __shfl_xor(tot.z, 32);
    tot.w += __shfl_xor(tot.w, 32);

    if (half == 0) {
        const float dd = dis[node];
        uint2 vd = ((const uint2*)(hh + (size_t)node * D))[l32];
        __half2 q0 = *(__half2*)&vd.x, q1 = *(__half2*)&vd.y;
        float2 f0 = __half22float2(q0), f1 = __half22float2(q1);
        float4 o;
        o.x = fmaxf(dd * (tot.x + f0.x), 0.f) * 0.125f;
        o.y = fmaxf(dd * (tot.y + f0.y), 0.f) * 0.125f;
        o.z = fmaxf(dd * (tot.z + f1.x), 0.f) * 0.125f;
        o.w = fmaxf(dd * (tot.w + f1.y), 0.f) * 0.125f;
        ((float4*)(out + (size_t)node * D))[l32] = o;
    }
}

extern "C" void kernel_launch(void* const* d_in, const int* in_sizes, int n_in,
                              void* d_out, int out_size, void* d_ws, size_t ws_size,
                              hipStream_t stream) {
    const float* x  = (const float*)d_in[0];
    const int*   ei = (const int*)d_in[1];   // [2, E] int32
    const float* W  = (const float*)d_in[2];
    const float* b  = (const float*)d_in[3];
    float* out = (float*)d_out;

    // workspace layout (~45 MB)
    __half*        hh     = (__half*)d_ws;                              // N*D halfs (25.6 MB)
    float*         dis    = (float*)(hh + (size_t)N_NODES * D);         // N floats
    int*           offs   = (int*)(dis + N_NODES);                      // N
    int*           offe   = offs + N_NODES;                             // N
    int*           sorted = offe + N_NODES;                             // NBUK*CAP (8 MB)
    unsigned int*  dstbin = (unsigned int*)(sorted + (size_t)NBUK * CAP);   // NBUK*CAP (8 MB)
    unsigned char* srcbin = (unsigned char*)(dstbin + (size_t)NBUK * CAP);  // NBUK*CAP bytes
    int*           cnt_d  = (int*)(srcbin + (size_t)NBUK * CAP);        // NBUK
    int*           cnt_s  = cnt_d + NBUK;                               // NBUK

    hipMemsetAsync(cnt_d, 0, 2 * NBUK * sizeof(int), stream);

    bin_scatter_kernel<<<NB_E, 256, 0, stream>>>(ei, cnt_d, cnt_s, dstbin, srcbin);
    bucket_build_kernel<<<NBUK, 256, 0, stream>>>(dstbin, srcbin, cnt_d, cnt_s,
                                                  offs, offe, sorted, dis);
    gemm_kernel<<<N_NODES / BM, 256, 0, stream>>>(x, W, b, dis, hh);
    gather_kernel<<<(N_NODES + 3) / 4, 256, 0, stream>>>(sorted, offs, offe, dis, hh, out);
}